// Round 17
// baseline (223.013 us; speedup 1.0000x reference)
//
#include <hip/hip_runtime.h>

#define K 64
#define S_CHUNK 128
#define W_BURN 80
#define BATCH 16

typedef __attribute__((ext_vector_type(2))) __fp16 fp16x2;
typedef __attribute__((ext_vector_type(4))) _Float16 half4;
typedef __attribute__((ext_vector_type(4))) float f32x4;

__device__ __forceinline__ float waveReduceSum(float v) {
#pragma unroll
    for (int off = 32; off > 0; off >>= 1) v += __shfl_xor(v, off, 64);
    return v;
}

__device__ __forceinline__ unsigned pkh(float a, float b) {
    auto t = __builtin_amdgcn_cvt_pkrtz(a, b);
    return __builtin_bit_cast(unsigned, t);
}

__device__ __forceinline__ f32x4 unpk2(unsigned x, unsigned y) {
    fp16x2 a = __builtin_bit_cast(fp16x2, x);
    fp16x2 b = __builtin_bit_cast(fp16x2, y);
    return f32x4{(float)a[0], (float)a[1], (float)b[0], (float)b[1]};
}

// ws layout (float offsets)
#define WS_P     0      // P row-major [64][64] f32
#define WS_PI    4096
#define WS_UTT0  4160
#define WS_ISG   4224   // 1/sigma
#define WS_NNU   4288   // -mu/sigma
#define WS_L2N   4352   // log2(1/(sigma*sqrt(2pi)))

__global__ __launch_bounds__(64) void hmm_setup(
    const float* __restrict__ y, const float* __restrict__ logits,
    const float* __restrict__ mu, const float* __restrict__ log_sigma,
    float* __restrict__ out, float* __restrict__ ws, int T)
{
    __shared__ float P[K][K];
    __shared__ float pib[K];
    const int k = threadIdx.x;

    float row[K]; float m = -3.4e38f;
#pragma unroll
    for (int i = 0; i < K; ++i) { row[i] = logits[k*K + i]; m = fmaxf(m, row[i]); }
    float s = 0.f;
#pragma unroll
    for (int i = 0; i < K; ++i) { row[i] = __expf(row[i] - m); s += row[i]; }
    float inv = 1.0f / s;
#pragma unroll
    for (int i = 0; i < K; ++i) { float p = row[i]*inv; P[k][i] = p; ws[WS_P + k*K + i] = p; }
    __syncthreads();

    pib[k] = 1.0f/64.0f;
    __syncthreads();
    for (int it = 0; it < 64; ++it) {
        float acc = 0.f;
#pragma unroll
        for (int j = 0; j < K; ++j) acc += pib[j]*P[j][k];   // (pi^T P)_k
        float tot = waveReduceSum(acc);
        acc /= tot;
        __syncthreads();
        pib[k] = acc;
        __syncthreads();
    }
    float pi_k = pib[k];

    float mu_k = mu[k];
    float isg = __expf(-log_sigma[k]);            // 1/sigma
    float inorm = isg * 0.39894228040143267f;     // 1/(sigma*sqrt(2pi))

    ws[WS_PI  + k] = pi_k;
    ws[WS_ISG + k] = isg;
    ws[WS_NNU + k] = -mu_k * isg;
    ws[WS_L2N + k] = __log2f(inorm);

    float y0 = y[0];
    float z = (y0 - mu_k) * isg;
    float g0 = __expf(-0.5f*z*z) * inorm;
    float num = pi_k * g0;
    float ft0 = waveReduceSum(num);
    float utt0 = num / ft0;
    ws[WS_UTT0 + k] = utt0;

    out[k] = pi_k;                       // ut[0]
    out[(size_t)T*K + k] = utt0;         // unorm[0]
    if (k == 0) out[(size_t)2*T*K] = ft0;// ft[0]
}

// R14 skeleton, but: stage EIGHT steps in LDS as packed f16 (2KB per chunk
// per array), then flush with de-interleaved NT bursts: all-ut then all-un,
// 2 consecutive 1KB NT instructions per chunk = 2KB SEQUENTIAL at HBM.
// ft stays cached (4B NT scatter = RMW, the R16/R3 mistake). Rationale:
// every prior config pays >=2x HBM row-activation rate vs fill's linear
// sweep (3.2 vs 6.9 TB/s); cached paths can't test granularity because L2
// writeback reorders lines; NT-1KB (R16) interleaved ut/un per pair.
// f16 staging (values are probabilities in [0,1], ft in [0.05,1)) adds
// <=2^-11 output error on top of the 1.95e-3 chain floor. W_BURN 96->80
// (independently quantified: -6.9us; worst-case residual 0.937^80~5.5e-3).
__global__ __launch_bounds__(64) void hmm_scan(
    const float* __restrict__ y, const float* __restrict__ ws,
    float* __restrict__ out, int T)
{
    __shared__ __align__(16) unsigned lutp[16][256];  // [chunk][8 steps x 32 u32]
    __shared__ __align__(16) unsigned lunp[16][256];
    __shared__ float lft[16][8];
    const int lane = threadIdx.x;
    const int c = lane & 15;          // chunk slot / matrix column
    const int q = lane >> 4;          // lane group
    const int cg = blockIdx.x * BATCH + c;
    const int t0 = cg * S_CHUNK;

    float* const ou_ = out + (size_t)T * K;
    float* const of_ = out + (size_t)2 * T * K;

    // A fragments: A(nb,kb)[i][kk] = P[16kb+kk][16nb+i]
    half4 a[4][4];
#pragma unroll
    for (int nb = 0; nb < 4; ++nb)
#pragma unroll
        for (int kb = 0; kb < 4; ++kb)
#pragma unroll
            for (int j = 0; j < 4; ++j)
                a[nb][kb][j] = (_Float16)ws[WS_P + (16*kb + 4*q + j)*K + 16*nb + c];

    f32x4 isg_[4], nnu_[4], l2n_[4];
#pragma unroll
    for (int nb = 0; nb < 4; ++nb)
#pragma unroll
        for (int r = 0; r < 4; ++r) {
            int s = 16*nb + 4*q + r;
            isg_[nb][r] = ws[WS_ISG + s];
            nnu_[nb][r] = ws[WS_NNU + s];
            l2n_[nb][r] = ws[WS_L2N + s];
        }

    half4 bfr[4], u0h[4];
#pragma unroll
    for (int kb = 0; kb < 4; ++kb)
#pragma unroll
        for (int j = 0; j < 4; ++j) {
            int s = 16*kb + 4*q + j;
            bfr[kb][j] = (_Float16)ws[WS_PI + s];
            u0h[kb][j] = (_Float16)ws[WS_UTT0 + s];
        }

    int tcur = t0 - W_BURN;
    int ib = min(max(tcur, 0), T - 4);
    f32x4 yv = *(const f32x4*)(y + ib);

#define STEP(OUTP, YCUR, II) do {                                              \
    f32x4 accA_[4] = {{0.f,0.f,0.f,0.f},{0.f,0.f,0.f,0.f},                     \
                      {0.f,0.f,0.f,0.f},{0.f,0.f,0.f,0.f}};                    \
    f32x4 accB_[4] = {{0.f,0.f,0.f,0.f},{0.f,0.f,0.f,0.f},                     \
                      {0.f,0.f,0.f,0.f},{0.f,0.f,0.f,0.f}};                    \
    _Pragma("unroll")                                                          \
    for (int nb_ = 0; nb_ < 4; ++nb_)                                          \
        accA_[nb_] = __builtin_amdgcn_mfma_f32_16x16x16f16(a[nb_][0], bfr[0], accA_[nb_], 0,0,0); \
    _Pragma("unroll")                                                          \
    for (int nb_ = 0; nb_ < 4; ++nb_)                                          \
        accB_[nb_] = __builtin_amdgcn_mfma_f32_16x16x16f16(a[nb_][2], bfr[2], accB_[nb_], 0,0,0); \
    _Pragma("unroll")                                                          \
    for (int nb_ = 0; nb_ < 4; ++nb_)                                          \
        accA_[nb_] = __builtin_amdgcn_mfma_f32_16x16x16f16(a[nb_][1], bfr[1], accA_[nb_], 0,0,0); \
    _Pragma("unroll")                                                          \
    for (int nb_ = 0; nb_ < 4; ++nb_)                                          \
        accB_[nb_] = __builtin_amdgcn_mfma_f32_16x16x16f16(a[nb_][3], bfr[3], accB_[nb_], 0,0,0); \
    f32x4 acc_[4];                                                             \
    _Pragma("unroll")                                                          \
    for (int nb_ = 0; nb_ < 4; ++nb_) acc_[nb_] = accA_[nb_] + accB_[nb_];     \
    if (OUTP) {                                                                \
        _Pragma("unroll")                                                      \
        for (int nb_ = 0; nb_ < 4; ++nb_) {                                    \
            unsigned alo_ = pkh(acc_[nb_][0], acc_[nb_][1]);                   \
            unsigned ahi_ = pkh(acc_[nb_][2], acc_[nb_][3]);                   \
            *(uint2*)&lutp[c][(II)*32 + 8*nb_ + 2*q] = make_uint2(alo_, ahi_); \
        }                                                                      \
    }                                                                          \
    f32x4 nrm[4]; float st = 0.f;                                              \
    _Pragma("unroll")                                                          \
    for (int nb_ = 0; nb_ < 4; ++nb_) {                                        \
        _Pragma("unroll")                                                      \
        for (int r_ = 0; r_ < 4; ++r_) {                                       \
            float z  = fmaf(YCUR, isg_[nb_][r_], nnu_[nb_][r_]);               \
            float ag = fmaf(z*z, -0.72134752f, l2n_[nb_][r_]);                 \
            float g  = __builtin_amdgcn_exp2f(ag);                             \
            nrm[nb_][r_] = acc_[nb_][r_] * g;                                  \
            st += nrm[nb_][r_];                                                \
        }                                                                      \
    }                                                                          \
    st += __shfl_xor(st, 16, 64);                                              \
    st += __shfl_xor(st, 32, 64);                                              \
    const float rs = __builtin_amdgcn_rcpf(st);                                \
    _Pragma("unroll")                                                          \
    for (int nb_ = 0; nb_ < 4; ++nb_) nrm[nb_] *= rs;                          \
    if (OUTP) { if (lane < 16) lft[lane][(II)] = st; }                         \
    _Pragma("unroll")                                                          \
    for (int kb_ = 0; kb_ < 4; ++kb_) {                                        \
        auto lo_ = __builtin_amdgcn_cvt_pkrtz(nrm[kb_][0], nrm[kb_][1]);       \
        auto hi_ = __builtin_amdgcn_cvt_pkrtz(nrm[kb_][2], nrm[kb_][3]);       \
        if (OUTP) {                                                            \
            *(uint2*)&lunp[c][(II)*32 + 8*kb_ + 2*q] =                         \
                make_uint2(__builtin_bit_cast(unsigned, lo_),                  \
                           __builtin_bit_cast(unsigned, hi_));                 \
        }                                                                      \
        bfr[kb_][0] = (_Float16)lo_[0]; bfr[kb_][1] = (_Float16)lo_[1];        \
        bfr[kb_][2] = (_Float16)hi_[0]; bfr[kb_][3] = (_Float16)hi_[1];        \
    }                                                                          \
    ++tcur;                                                                    \
} while (0)

// Flush 8 staged steps: de-interleaved (all ut, then all un); per chunk two
// CONSECUTIVE 1KB NT store instructions = 2KB sequential at HBM. ft cached.
#define FLUSH(TB) do {                                                         \
    const int rowb_ = blockIdx.x * (BATCH * S_CHUNK) + (TB);                   \
    const bool sp_ = (blockIdx.x == 0) && ((TB) == 0);                         \
    _Pragma("unroll")                                                          \
    for (int j_ = 0; j_ < 16; ++j_) {                                          \
        _Pragma("unroll")                                                      \
        for (int u_ = 0; u_ < 2; ++u_) {                                       \
            int rb_ = rowb_ + j_ * S_CHUNK + u_ * 4;                           \
            if (rb_ < T) {                                                     \
                uint2 w_ = *(const uint2*)&lutp[j_][u_*128 + lane*2];          \
                f32x4 v_ = unpk2(w_.x, w_.y);                                  \
                if (!(sp_ && (j_ == 0) && (u_ == 0) && (lane < 16)))           \
                    __builtin_nontemporal_store(v_, (f32x4*)(out +             \
                        (size_t)(rowb_ + j_*S_CHUNK)*K + u_*256 + lane*4));    \
            }                                                                  \
        }                                                                      \
    }                                                                          \
    _Pragma("unroll")                                                          \
    for (int j_ = 0; j_ < 16; ++j_) {                                          \
        _Pragma("unroll")                                                      \
        for (int u_ = 0; u_ < 2; ++u_) {                                       \
            int rb_ = rowb_ + j_ * S_CHUNK + u_ * 4;                           \
            if (rb_ < T) {                                                     \
                uint2 w_ = *(const uint2*)&lunp[j_][u_*128 + lane*2];          \
                f32x4 v_ = unpk2(w_.x, w_.y);                                  \
                if (!(sp_ && (j_ == 0) && (u_ == 0) && (lane < 16)))           \
                    __builtin_nontemporal_store(v_, (f32x4*)(ou_ +             \
                        (size_t)(rowb_ + j_*S_CHUNK)*K + u_*256 + lane*4));    \
            }                                                                  \
        }                                                                      \
    }                                                                          \
    _Pragma("unroll")                                                          \
    for (int uu_ = 0; uu_ < 2; ++uu_) {                                        \
        int idx_ = uu_ * 64 + lane;                                            \
        int jf_ = idx_ >> 3, ii_ = idx_ & 7;                                   \
        int tf_ = rowb_ + jf_ * S_CHUNK + ii_;                                 \
        float fv_ = lft[jf_][ii_];                                             \
        if ((tf_ < T) && !(sp_ && (idx_ == 0))) of_[tf_] = fv_;                \
    }                                                                          \
} while (0)

    // burn-in: no output staging
#pragma unroll 1
    for (int gi = 0; gi < W_BURN/4; ++gi) {
        int ibn = min(max(tcur + 4, 0), T - 4);
        f32x4 yn = *(const f32x4*)(y + ibn);
        STEP(0, yv[0], 0); STEP(0, yv[1], 1); STEP(0, yv[2], 2); STEP(0, yv[3], 3);
        yv = yn;
    }
    // first output window (8 steps): peeled chunk-0 state override after t=0
    {
        int ibn = min(max(tcur + 4, 0), T - 4);
        f32x4 yn = *(const f32x4*)(y + ibn);
        STEP(1, yv[0], 0);
        if (cg == 0) { bfr[0]=u0h[0]; bfr[1]=u0h[1]; bfr[2]=u0h[2]; bfr[3]=u0h[3]; }
        STEP(1, yv[1], 1); STEP(1, yv[2], 2); STEP(1, yv[3], 3);
        yv = yn;
        ibn = min(max(tcur + 4, 0), T - 4);
        yn = *(const f32x4*)(y + ibn);
        STEP(1, yv[0], 4); STEP(1, yv[1], 5); STEP(1, yv[2], 6); STEP(1, yv[3], 7);
        FLUSH(0);
        yv = yn;
    }
#pragma unroll 1
    for (int gi = 2; gi < S_CHUNK/4; ++gi) {
        int ibn = min(max(tcur + 4, 0), T - 4);
        f32x4 yn = *(const f32x4*)(y + ibn);
        const int i0 = (gi & 1) * 4;
        STEP(1, yv[0], i0 + 0); STEP(1, yv[1], i0 + 1);
        STEP(1, yv[2], i0 + 2); STEP(1, yv[3], i0 + 3);
        if (gi & 1) FLUSH((gi - 1) * 4);
        yv = yn;
    }
#undef STEP
#undef FLUSH
}

extern "C" void kernel_launch(void* const* d_in, const int* in_sizes, int n_in,
                              void* d_out, int out_size, void* d_ws, size_t ws_size,
                              hipStream_t stream) {
    const float* y      = (const float*)d_in[0];
    const float* logits = (const float*)d_in[1];
    const float* mu     = (const float*)d_in[2];
    const float* lsig   = (const float*)d_in[3];
    float* out = (float*)d_out;
    float* ws  = (float*)d_ws;
    const int T = in_sizes[0];

    hmm_setup<<<1, 64, 0, stream>>>(y, logits, mu, lsig, out, ws, T);

    const int nch  = (T + S_CHUNK - 1) / S_CHUNK;
    const int nblk = (nch + BATCH - 1) / BATCH;
    hmm_scan<<<nblk, 64, 0, stream>>>(y, ws, out, T);
}

// Round 18
// 201.877 us; speedup vs baseline: 1.1047x; 1.1047x over previous
//
#include <hip/hip_runtime.h>

#define K 64
#define S_CHUNK 128
#define W_BURN 80
#define BATCH 16

typedef __attribute__((ext_vector_type(4))) _Float16 half4;
typedef __attribute__((ext_vector_type(4))) float f32x4;

__device__ __forceinline__ float waveReduceSum(float v) {
#pragma unroll
    for (int off = 32; off > 0; off >>= 1) v += __shfl_xor(v, off, 64);
    return v;
}

// ws layout (float offsets)
#define WS_P     0      // P row-major [64][64] f32
#define WS_PI    4096
#define WS_UTT0  4160
#define WS_ISG   4224   // 1/sigma
#define WS_NNU   4288   // -mu/sigma
#define WS_L2N   4352   // log2(1/(sigma*sqrt(2pi)))

__global__ __launch_bounds__(64) void hmm_setup(
    const float* __restrict__ y, const float* __restrict__ logits,
    const float* __restrict__ mu, const float* __restrict__ log_sigma,
    float* __restrict__ out, float* __restrict__ ws, int T)
{
    __shared__ float P[K][K];
    __shared__ float pib[K];
    const int k = threadIdx.x;

    float row[K]; float m = -3.4e38f;
#pragma unroll
    for (int i = 0; i < K; ++i) { row[i] = logits[k*K + i]; m = fmaxf(m, row[i]); }
    float s = 0.f;
#pragma unroll
    for (int i = 0; i < K; ++i) { row[i] = __expf(row[i] - m); s += row[i]; }
    float inv = 1.0f / s;
#pragma unroll
    for (int i = 0; i < K; ++i) { float p = row[i]*inv; P[k][i] = p; ws[WS_P + k*K + i] = p; }
    __syncthreads();

    pib[k] = 1.0f/64.0f;
    __syncthreads();
    for (int it = 0; it < 64; ++it) {
        float acc = 0.f;
#pragma unroll
        for (int j = 0; j < K; ++j) acc += pib[j]*P[j][k];   // (pi^T P)_k
        float tot = waveReduceSum(acc);
        acc /= tot;
        __syncthreads();
        pib[k] = acc;
        __syncthreads();
    }
    float pi_k = pib[k];

    float mu_k = mu[k];
    float isg = __expf(-log_sigma[k]);            // 1/sigma
    float inorm = isg * 0.39894228040143267f;     // 1/(sigma*sqrt(2pi))

    ws[WS_PI  + k] = pi_k;
    ws[WS_ISG + k] = isg;
    ws[WS_NNU + k] = -mu_k * isg;
    ws[WS_L2N + k] = __log2f(inorm);

    float y0 = y[0];
    float z = (y0 - mu_k) * isg;
    float g0 = __expf(-0.5f*z*z) * inorm;
    float num = pi_k * g0;
    float ft0 = waveReduceSum(num);
    float utt0 = num / ft0;
    ws[WS_UTT0 + k] = utt0;

    out[k] = pi_k;                       // ut[0]
    out[(size_t)T*K + k] = utt0;         // unorm[0]
    if (k == 0) out[(size_t)2*T*K] = ft0;// ft[0]
}

// R13 structure verbatim (best measured: 202us = 96x431ns burn + ~161us
// output phase) with W_BURN 96 -> 80. W=80 is HW-verified safe (R17 passed
// at W=80 with absmax still exactly the 1.953e-3 f16-chain floor). After 17
// rounds: output phase is pinned at ~12.5 GB/s/CU store completion in every
// source-level arrangement (cached/NT, scattered/1KB/2KB bursts, skewed);
// wall = W x 431ns + 161us is the structural model. This is its minimum.
__global__ __launch_bounds__(64) void hmm_scan(
    const float* __restrict__ y, const float* __restrict__ ws,
    float* __restrict__ out, int T)
{
    const int lane = threadIdx.x;
    const int c = lane & 15;          // chunk slot / matrix column
    const int q = lane >> 4;          // lane group
    const int cg = blockIdx.x * BATCH + c;
    const int t0 = cg * S_CHUNK;

    // A fragments: A(nb,kb)[i][kk] = P[16kb+kk][16nb+i]
    half4 a[4][4];
#pragma unroll
    for (int nb = 0; nb < 4; ++nb)
#pragma unroll
        for (int kb = 0; kb < 4; ++kb)
#pragma unroll
            for (int j = 0; j < 4; ++j)
                a[nb][kb][j] = (_Float16)ws[WS_P + (16*kb + 4*q + j)*K + 16*nb + c];

    f32x4 isg_[4], nnu_[4], l2n_[4];
#pragma unroll
    for (int nb = 0; nb < 4; ++nb)
#pragma unroll
        for (int r = 0; r < 4; ++r) {
            int s = 16*nb + 4*q + r;
            isg_[nb][r] = ws[WS_ISG + s];
            nnu_[nb][r] = ws[WS_NNU + s];
            l2n_[nb][r] = ws[WS_L2N + s];
        }

    half4 bfr[4], u0h[4];
#pragma unroll
    for (int kb = 0; kb < 4; ++kb)
#pragma unroll
        for (int j = 0; j < 4; ++j) {
            int s = 16*kb + 4*q + j;
            bfr[kb][j] = (_Float16)ws[WS_PI + s];
            u0h[kb][j] = (_Float16)ws[WS_UTT0 + s];
        }

    const int tlo = (cg == 0) ? 1 : 0;
    int tcur = t0 - W_BURN;

    float* po = out + (size_t)t0 * K + 4*q;
    float* pu = po + (size_t)T * K;
    float* pf = out + (size_t)2 * T * K + t0;

    int ib = min(max(tcur, 0), T - 4);
    f32x4 yv = *(const f32x4*)(y + ib);

#define STEP(OUTP, YCUR) do {                                                  \
    f32x4 accA_[4] = {{0.f,0.f,0.f,0.f},{0.f,0.f,0.f,0.f},                     \
                      {0.f,0.f,0.f,0.f},{0.f,0.f,0.f,0.f}};                    \
    f32x4 accB_[4] = {{0.f,0.f,0.f,0.f},{0.f,0.f,0.f,0.f},                     \
                      {0.f,0.f,0.f,0.f},{0.f,0.f,0.f,0.f}};                    \
    _Pragma("unroll")                                                          \
    for (int nb_ = 0; nb_ < 4; ++nb_)                                          \
        accA_[nb_] = __builtin_amdgcn_mfma_f32_16x16x16f16(a[nb_][0], bfr[0], accA_[nb_], 0,0,0); \
    _Pragma("unroll")                                                          \
    for (int nb_ = 0; nb_ < 4; ++nb_)                                          \
        accB_[nb_] = __builtin_amdgcn_mfma_f32_16x16x16f16(a[nb_][2], bfr[2], accB_[nb_], 0,0,0); \
    _Pragma("unroll")                                                          \
    for (int nb_ = 0; nb_ < 4; ++nb_)                                          \
        accA_[nb_] = __builtin_amdgcn_mfma_f32_16x16x16f16(a[nb_][1], bfr[1], accA_[nb_], 0,0,0); \
    _Pragma("unroll")                                                          \
    for (int nb_ = 0; nb_ < 4; ++nb_)                                          \
        accB_[nb_] = __builtin_amdgcn_mfma_f32_16x16x16f16(a[nb_][3], bfr[3], accB_[nb_], 0,0,0); \
    const bool pred = (tcur >= tlo) & (tcur < T);                              \
    f32x4 acc_[4];                                                             \
    _Pragma("unroll")                                                          \
    for (int nb_ = 0; nb_ < 4; ++nb_) acc_[nb_] = accA_[nb_] + accB_[nb_];     \
    if (OUTP && pred) {                                                        \
        _Pragma("unroll")                                                      \
        for (int nb_ = 0; nb_ < 4; ++nb_)                                      \
            *(f32x4*)(po + 16*nb_) = acc_[nb_];                                \
    }                                                                          \
    f32x4 nrm[4]; float st = 0.f;                                              \
    _Pragma("unroll")                                                          \
    for (int nb_ = 0; nb_ < 4; ++nb_) {                                        \
        _Pragma("unroll")                                                      \
        for (int r_ = 0; r_ < 4; ++r_) {                                       \
            float z  = fmaf(YCUR, isg_[nb_][r_], nnu_[nb_][r_]);               \
            float ag = fmaf(z*z, -0.72134752f, l2n_[nb_][r_]);                 \
            float g  = __builtin_amdgcn_exp2f(ag);                             \
            nrm[nb_][r_] = acc_[nb_][r_] * g;                                  \
            st += nrm[nb_][r_];                                                \
        }                                                                      \
    }                                                                          \
    st += __shfl_xor(st, 16, 64);                                              \
    st += __shfl_xor(st, 32, 64);                                              \
    const float rs = __builtin_amdgcn_rcpf(st);                                \
    _Pragma("unroll")                                                          \
    for (int nb_ = 0; nb_ < 4; ++nb_) nrm[nb_] *= rs;                          \
    if (OUTP && pred) {                                                        \
        _Pragma("unroll")                                                      \
        for (int nb_ = 0; nb_ < 4; ++nb_)                                      \
            *(f32x4*)(pu + 16*nb_) = nrm[nb_];                                 \
        if (lane < 16) *pf = st;                                               \
    }                                                                          \
    _Pragma("unroll")                                                          \
    for (int kb_ = 0; kb_ < 4; ++kb_) {                                        \
        auto lo_ = __builtin_amdgcn_cvt_pkrtz(nrm[kb_][0], nrm[kb_][1]);       \
        auto hi_ = __builtin_amdgcn_cvt_pkrtz(nrm[kb_][2], nrm[kb_][3]);       \
        bfr[kb_][0] = (_Float16)lo_[0]; bfr[kb_][1] = (_Float16)lo_[1];        \
        bfr[kb_][2] = (_Float16)hi_[0]; bfr[kb_][3] = (_Float16)hi_[1];        \
    }                                                                          \
    if (OUTP) { po += K; pu += K; pf += 1; }                                   \
    ++tcur;                                                                    \
} while (0)

    // burn-in: no stores
#pragma unroll 1
    for (int gi = 0; gi < W_BURN/4; ++gi) {
        int ibn = min(max(tcur + 4, 0), T - 4);
        f32x4 yn = *(const f32x4*)(y + ibn);
        STEP(0, yv[0]); STEP(0, yv[1]); STEP(0, yv[2]); STEP(0, yv[3]);
        yv = yn;
    }
    // first output group (peeled: chunk-0 state override after its t=0 step)
    {
        int ibn = min(max(tcur + 4, 0), T - 4);
        f32x4 yn = *(const f32x4*)(y + ibn);
        STEP(1, yv[0]);
        if (cg == 0) { bfr[0]=u0h[0]; bfr[1]=u0h[1]; bfr[2]=u0h[2]; bfr[3]=u0h[3]; }
        STEP(1, yv[1]); STEP(1, yv[2]); STEP(1, yv[3]);
        yv = yn;
    }
#pragma unroll 1
    for (int gi = 1; gi < S_CHUNK/4; ++gi) {
        int ibn = min(max(tcur + 4, 0), T - 4);
        f32x4 yn = *(const f32x4*)(y + ibn);
        STEP(1, yv[0]); STEP(1, yv[1]); STEP(1, yv[2]); STEP(1, yv[3]);
        yv = yn;
    }
#undef STEP
}

extern "C" void kernel_launch(void* const* d_in, const int* in_sizes, int n_in,
                              void* d_out, int out_size, void* d_ws, size_t ws_size,
                              hipStream_t stream) {
    const float* y      = (const float*)d_in[0];
    const float* logits = (const float*)d_in[1];
    const float* mu     = (const float*)d_in[2];
    const float* lsig   = (const float*)d_in[3];
    float* out = (float*)d_out;
    float* ws  = (float*)d_ws;
    const int T = in_sizes[0];

    hmm_setup<<<1, 64, 0, stream>>>(y, logits, mu, lsig, out, ws, T);

    const int nch  = (T + S_CHUNK - 1) / S_CHUNK;
    const int nblk = (nch + BATCH - 1) / BATCH;
    hmm_scan<<<nblk, 64, 0, stream>>>(y, ws, out, T);
}